// Round 1
// baseline (478.022 us; speedup 1.0000x reference)
//
#include <hip/hip_runtime.h>
#include <hip/hip_bf16.h>

// Problem constants (fixed by reference setup_inputs).
#define T_TOTAL 2048
#define BATCH   128
#define NIN     256
#define NOUT    128

// Decomposition: T-chunks x B-chunks. Warm-up recomputes trace history.
// TC=128 -> 512 blocks = 2 blocks/CU (vs previous 256/1): a second resident
// block covers the per-group barrier + vmcnt stalls that kept the previous
// version at ~45% of its HBM floor. Requires VGPR<=128 (launch_bounds 512,4),
// achieved by float2 staging loads (halved VMEM instrs, halved prefetch regs).
#define TC      128                 // timesteps per block
#define BC      4                   // batches per block
#define WARM    32                  // warm-up steps (0.5^32 ~ 2e-10 truncation)
#define G       4                   // timesteps per MFMA K-group (K = G*BC = 16)
#define NTC     (T_TOTAL / TC)      // 16
#define NBC     (BATCH / BC)        // 32
#define NBLOCKS (NTC * NBC)         // 512  (2 blocks/CU)
#define NG      (TC / G)            // 32 K-groups per block

#define ROWU      24                // ushorts per LDS row: 16 data + 8 pad = 48 B
#define ROWD      12                // dwords per LDS row
#define OUT_ELEMS (NOUT * NIN)      // 32768

static_assert(NG % 2 == 0, "pipeline needs even group count");

typedef __attribute__((ext_vector_type(8)))  __bf16 bf16x8;
typedef __attribute__((ext_vector_type(2)))  __bf16 bf16x2;
typedef __attribute__((ext_vector_type(16))) float  f32x16;

// packed f32x2 -> bf16x2 (v_cvt_pk_bf16_f32 on gfx950, RTNE)
static __device__ __forceinline__ unsigned pack_bf16(float a, float b) {
    bf16x2 v = { (__bf16)a, (__bf16)b };
    union { bf16x2 v; unsigned u; } c; c.v = v; return c.u;
}

// Main fused kernel: fp32 trace scan in registers + bf16 MFMA accumulation.
// 2-deep register prefetch (loads for group g issued at g-2) + 2 blocks/CU
// so one block's barrier drain overlaps the other's loads.
//
// k-mapping (consistent on A and B sides): k = b_local*4 + q, q in [0,G).
// LDS rows hold 16 bf16 (32 B data) at 48 B pitch; dword column is
// XOR-swizzled at 16B granularity by row bit 5 (kdw ^= ((row>>5)&1)<<2),
// applied identically on write and on the b128 read's half-select so the
// k-order inside each 16B fragment is preserved.
__global__ __launch_bounds__(512, 4)
void stdp_main(const float* __restrict__ in, const float* __restrict__ outs,
               float* __restrict__ dst, int nslots, int use_atomic)
{
    __shared__ unsigned short tr_lds[2][NIN * ROWU];   // 2 x 12 KB, B operand (trace, n=i)
    __shared__ unsigned short ot_lds[2][NOUT * ROWU];  // 2 x  6 KB, A operand (out-spikes, m=o)

    const int tid = threadIdx.x;
    const int bc  = blockIdx.x % NBC;
    const int tc  = blockIdx.x / NBC;
    const int b0  = bc * BC;
    const int t0  = tc * TC;

    // trace ownership: thread -> (i = 2*(tid&127), 2*(tid&127)+1 ; batch b0+btr)
    const int i0  = (tid & 127) * 2;
    const int btr = (tid >> 7) & 3;
    // out staging ownership: thread -> (o = 2*(tid&63), +1 ; batch b0+bo ; q in {2*q2, 2*q2+1})
    const int o0  = (tid & 63) * 2;
    const int bo  = (tid >> 6) & 3;
    const int q2  = (tid >> 8) & 1;

    const float2* __restrict__ inp  =
        (const float2*)(in + (size_t)(b0 + btr) * NIN + i0);
    const float2* __restrict__ outp =
        (const float2*)(outs + (size_t)(b0 + bo) * NOUT + o0);
    const size_t IST = (size_t)BATCH * NIN  / 2;   // float2 stride per timestep
    const size_t OST = (size_t)BATCH * NOUT / 2;

    float tr0 = 0.f, tr1 = 0.f;

    // ---- warm-up: trace scan only (no MFMA), float2 loads ----
    if (tc > 0) {
        for (int t = t0 - WARM; t < t0; t += 8) {
            float2 v[8];
#pragma unroll
            for (int u = 0; u < 8; ++u) v[u] = inp[(size_t)(t + u) * IST];
#pragma unroll
            for (int u = 0; u < 8; ++u) {
                tr0 = 0.5f * tr0 + v[u].x;
                tr1 = 0.5f * tr1 + v[u].y;
            }
        }
    }

    f32x16 acc[4];
#pragma unroll
    for (int j = 0; j < 4; ++j) acc[j] = (f32x16)(0.f);

    const int lane  = tid & 63;
    const int wv    = tid >> 6;          // 8 waves
    const int mt    = wv & 3;            // m-tile (NOUT rows mt*32..+31)
    const int ntb   = (wv >> 2) * 4;     // n-tile base (4 tiles per wave)
    const int l31   = lane & 31;
    const int khalf = lane >> 5;         // 0/1 -> logical k offset 0/8

    // LDS write offsets (dword units), XOR-swizzled by row bit 5.
    const int vtr  = (i0 >> 5) & 1;      // same for rows i0 and i0+1 (i0 even)
    const int vot  = (o0 >> 5) & 1;
    const int kb   = btr * 2;            // trace logical dword cols kb, kb+1
    const int ko   = bo * 2 + q2;        // out logical dword col
    const int trw0 = i0 * ROWD + ((kb)     ^ (vtr << 2));
    const int trw1 = i0 * ROWD + ((kb + 1) ^ (vtr << 2));
    const int otw0 = o0 * ROWD + ((ko)     ^ (vot << 2));

    // A-frag read offset (ushort units): row = mt*32+l31, swizzle bit = mt&1.
    const int ard = (mt * 32 + l31) * ROWU + ((khalf ^ (mt & 1)) << 3);
    // B-frag read base: row = (ntb+j)*32+l31, swizzle bit = (ntb+j)&1.
    const int brd0 = l31 * ROWU;

    // 2-stage register prefetch buffers (float2: 24 floats total)
    float2 PI[2][G];
    float2 PO[2][2];

    auto load_stage = [&](int s, int g) {
        const int tg = t0 + g * G;
#pragma unroll
        for (int q = 0; q < G; ++q) PI[s][q] = inp[(size_t)(tg + q) * IST];
#pragma unroll
        for (int u = 0; u < 2; ++u) PO[s][u] = outp[(size_t)(tg + 2 * q2 + u) * OST];
    };

    auto body = [&](int s, int g) {
        // consume stage s: trace recurrence (exact fp32), packed bf16 cvt
        float a0[G], a1[G];
#pragma unroll
        for (int q = 0; q < G; ++q) {
            tr0 = 0.5f * tr0 + PI[s][q].x;
            tr1 = 0.5f * tr1 + PI[s][q].y;
            a0[q] = tr0; a1[q] = tr1;
        }
        const unsigned w00 = pack_bf16(a0[0], a0[1]);   // row i0  , k=btr*4+{0,1}
        const unsigned w01 = pack_bf16(a0[2], a0[3]);   // row i0  , k=btr*4+{2,3}
        const unsigned w10 = pack_bf16(a1[0], a1[1]);   // row i0+1
        const unsigned w11 = pack_bf16(a1[2], a1[3]);
        const unsigned wo0 = pack_bf16(PO[s][0].x, PO[s][1].x); // row o0  , k=bo*4+2q2+{0,1}
        const unsigned wo1 = pack_bf16(PO[s][0].y, PO[s][1].y); // row o0+1

        // stage s is free: issue loads for group g+2 (2-deep pipeline)
        if (g + 2 < NG) load_stage(s, g + 2);

        unsigned* trl = (unsigned*)&tr_lds[s][0];
        unsigned* otl = (unsigned*)&ot_lds[s][0];
        trl[trw0]        = w00;
        trl[trw1]        = w01;
        trl[trw0 + ROWD] = w10;
        trl[trw1 + ROWD] = w11;
        otl[otw0]        = wo0;
        otl[otw0 + ROWD] = wo1;

        __syncthreads();   // single barrier per group (WAR-safe: see pipeline note)

        const bf16x8 a = *(const bf16x8*)&ot_lds[s][ard];
#pragma unroll
        for (int j = 0; j < 4; ++j) {
            const int bn = ntb + j;
            const bf16x8 b = *(const bf16x8*)
                &tr_lds[s][bn * (32 * ROWU) + brd0 + ((khalf ^ (bn & 1)) << 3)];
            acc[j] = __builtin_amdgcn_mfma_f32_32x32x16_bf16(a, b, acc[j], 0, 0, 0);
        }
    };

    load_stage(0, 0);
    load_stage(1, 1);
    for (int gg = 0; gg < NG; gg += 2) {
        body(0, gg);
        body(1, gg + 1);
    }

    // ---- epilogue: D[row, col] -> dw[o = mt*32+row, i = (ntb+j)*32+col] ----
    float* base = dst + (size_t)(use_atomic ? (blockIdx.x % nslots) : blockIdx.x) * OUT_ELEMS;
#pragma unroll
    for (int j = 0; j < 4; ++j) {
        const int icol = (ntb + j) * 32 + l31;
#pragma unroll
        for (int r = 0; r < 16; ++r) {
            const int row = (r & 3) + 8 * (r >> 2) + 4 * khalf;
            const int o   = mt * 32 + row;
            const float v = acc[j][r];
            if (use_atomic) atomicAdd(&base[o * NIN + icol], v);
            else            base[o * NIN + icol] = v;
        }
    }
}

__global__ void zero_kernel(float* p, int n) {
    int i = blockIdx.x * blockDim.x + threadIdx.x;
    if (i < n) p[i] = 0.f;
}

__global__ __launch_bounds__(256)
void reduce_kernel(const float* __restrict__ ws, float* __restrict__ outp, int nslots) {
    const int idx = blockIdx.x * 256 + threadIdx.x;
    float s = 0.f;
    int k = 0;
    for (; k + 16 <= nslots; k += 16) {
        float v[16];
#pragma unroll
        for (int u = 0; u < 16; ++u) v[u] = ws[(size_t)(k + u) * OUT_ELEMS + idx];
#pragma unroll
        for (int u = 0; u < 16; ++u) s += v[u];
    }
    for (; k < nslots; ++k) s += ws[(size_t)k * OUT_ELEMS + idx];
    outp[idx] = s;
}

extern "C" void kernel_launch(void* const* d_in, const int* in_sizes, int n_in,
                              void* d_out, int out_size, void* d_ws, size_t ws_size,
                              hipStream_t stream) {
    const float* in   = (const float*)d_in[0];
    const float* outs = (const float*)d_in[1];
    float* out = (float*)d_out;
    float* ws  = (float*)d_ws;

    const size_t slot_bytes = (size_t)OUT_ELEMS * sizeof(float);

    if (ws_size >= (size_t)NBLOCKS * slot_bytes) {
        // plain per-block partials + reduce (preferred)
        stdp_main<<<NBLOCKS, 512, 0, stream>>>(in, outs, ws, NBLOCKS, 0);
        reduce_kernel<<<OUT_ELEMS / 256, 256, 0, stream>>>(ws, out, NBLOCKS);
    } else if (ws_size >= 16 * slot_bytes) {
        // 16 shared slots, atomic accumulation
        zero_kernel<<<(16 * OUT_ELEMS + 255) / 256, 256, 0, stream>>>(ws, 16 * OUT_ELEMS);
        stdp_main<<<NBLOCKS, 512, 0, stream>>>(in, outs, ws, 16, 1);
        reduce_kernel<<<OUT_ELEMS / 256, 256, 0, stream>>>(ws, out, 16);
    } else {
        // last resort: atomics straight into d_out
        zero_kernel<<<(OUT_ELEMS + 255) / 256, 256, 0, stream>>>(out, OUT_ELEMS);
        stdp_main<<<NBLOCKS, 512, 0, stream>>>(in, outs, out, 1, 1);
    }
}

// Round 2
// 476.100 us; speedup vs baseline: 1.0040x; 1.0040x over previous
//
#include <hip/hip_runtime.h>
#include <hip/hip_bf16.h>

// Problem constants (fixed by reference setup_inputs).
#define T_TOTAL 2048
#define BATCH   128
#define NIN     256
#define NOUT    128

// Decomposition: T-chunks x B-chunks. Warm-up recomputes trace history.
#define TC      128                 // timesteps per block
#define BC      4                   // batches per block
#define WARM    32                  // warm-up steps (0.5^32 ~ 2e-10 truncation)
#define G       4                   // timesteps per MFMA K-group (K = G*BC = 16)
#define NTC     (T_TOTAL / TC)      // 16
#define NBC     (BATCH / BC)        // 32
#define NBLOCKS (NTC * NBC)         // 512  (2 blocks/CU)
#define NG      (TC / G)            // 32 K-groups per block

#define ROWU      24                // ushorts per LDS row: 16 data + 8 pad = 48 B
#define ROWD      12                // dwords per LDS row
#define OUT_ELEMS (NOUT * NIN)      // 32768

static_assert(NG % 2 == 0, "pipeline needs even group count");

typedef __attribute__((ext_vector_type(8)))  __bf16 bf16x8;
typedef __attribute__((ext_vector_type(2)))  __bf16 bf16x2;
typedef __attribute__((ext_vector_type(16))) float  f32x16;

// packed f32x2 -> bf16x2 (v_cvt_pk_bf16_f32 on gfx950, RTNE)
static __device__ __forceinline__ unsigned pack_bf16(float a, float b) {
    bf16x2 v = { (__bf16)a, (__bf16)b };
    union { bf16x2 v; unsigned u; } c; c.v = v; return c.u;
}

// Raw barrier WITHOUT the vmcnt(0) drain that HIP __syncthreads() emits.
// lgkmcnt(0) before s_barrier makes this wave's ds_writes visible (and its
// ds_reads complete, which covers the stage-s WAR two groups later).
// sched_barrier(0) after s_barrier pins the following ds_reads below the
// barrier (raw s_barrier is not a compiler memory fence).
// Global prefetch loads deliberately stay IN FLIGHT across the barrier;
// the compiler's exact vmcnt bookkeeping waits only when PI/PO are consumed.
static __device__ __forceinline__ void block_sync_lds_only() {
    asm volatile("s_waitcnt lgkmcnt(0)" ::: "memory");
    __builtin_amdgcn_s_barrier();
    __builtin_amdgcn_sched_barrier(0);
}

// Main fused kernel: fp32 trace scan in registers + bf16 MFMA accumulation.
// 2-deep register prefetch (loads for group g issued at g-2) + raw barriers
// so prefetch loads survive across group boundaries (counted-vmcnt pattern).
//
// k-mapping (consistent on A and B sides): k = b_local*4 + q, q in [0,G).
// LDS rows hold 16 bf16 (32 B data) at 48 B pitch; dword column is
// XOR-swizzled at 16B granularity by row bit 5 (kdw ^= ((row>>5)&1)<<2),
// applied identically on write and on the b128 read's half-select so the
// k-order inside each 16B fragment is preserved.
__global__ __launch_bounds__(512, 4)
void stdp_main(const float* __restrict__ in, const float* __restrict__ outs,
               float* __restrict__ dst, int nslots, int use_atomic)
{
    __shared__ unsigned short tr_lds[2][NIN * ROWU];   // 2 x 12 KB, B operand (trace, n=i)
    __shared__ unsigned short ot_lds[2][NOUT * ROWU];  // 2 x  6 KB, A operand (out-spikes, m=o)

    const int tid = threadIdx.x;
    const int bc  = blockIdx.x % NBC;
    const int tc  = blockIdx.x / NBC;
    const int b0  = bc * BC;
    const int t0  = tc * TC;

    // trace ownership: thread -> (i = 2*(tid&127), 2*(tid&127)+1 ; batch b0+btr)
    const int i0  = (tid & 127) * 2;
    const int btr = (tid >> 7) & 3;
    // out staging ownership: thread -> (o = 2*(tid&63), +1 ; batch b0+bo ; q in {2*q2, 2*q2+1})
    const int o0  = (tid & 63) * 2;
    const int bo  = (tid >> 6) & 3;
    const int q2  = (tid >> 8) & 1;

    const float2* __restrict__ inp  =
        (const float2*)(in + (size_t)(b0 + btr) * NIN + i0);
    const float2* __restrict__ outp =
        (const float2*)(outs + (size_t)(b0 + bo) * NOUT + o0);
    const size_t IST = (size_t)BATCH * NIN  / 2;   // float2 stride per timestep
    const size_t OST = (size_t)BATCH * NOUT / 2;

    float tr0 = 0.f, tr1 = 0.f;

    // ---- warm-up: trace scan only (no MFMA), float2 loads ----
    if (tc > 0) {
        for (int t = t0 - WARM; t < t0; t += 8) {
            float2 v[8];
#pragma unroll
            for (int u = 0; u < 8; ++u) v[u] = inp[(size_t)(t + u) * IST];
#pragma unroll
            for (int u = 0; u < 8; ++u) {
                tr0 = 0.5f * tr0 + v[u].x;
                tr1 = 0.5f * tr1 + v[u].y;
            }
        }
    }

    f32x16 acc[4];
#pragma unroll
    for (int j = 0; j < 4; ++j) acc[j] = (f32x16)(0.f);

    const int lane  = tid & 63;
    const int wv    = tid >> 6;          // 8 waves
    const int mt    = wv & 3;            // m-tile (NOUT rows mt*32..+31)
    const int ntb   = (wv >> 2) * 4;     // n-tile base (4 tiles per wave)
    const int l31   = lane & 31;
    const int khalf = lane >> 5;         // 0/1 -> logical k offset 0/8

    // LDS write offsets (dword units), XOR-swizzled by row bit 5.
    const int vtr  = (i0 >> 5) & 1;      // same for rows i0 and i0+1 (i0 even)
    const int vot  = (o0 >> 5) & 1;
    const int kb   = btr * 2;            // trace logical dword cols kb, kb+1
    const int ko   = bo * 2 + q2;        // out logical dword col
    const int trw0 = i0 * ROWD + (kb ^ (vtr << 2));   // even: kb even, xor at bit 2
    const int otw0 = o0 * ROWD + (ko ^ (vot << 2));

    // A-frag read offset (ushort units): row = mt*32+l31, swizzle bit = mt&1.
    const int ard = (mt * 32 + l31) * ROWU + ((khalf ^ (mt & 1)) << 3);
    // B-frag read base: row = (ntb+j)*32+l31, swizzle bit = (ntb+j)&1.
    const int brd0 = l31 * ROWU;

    // 2-stage register prefetch buffers (float2: 24 floats total)
    float2 PI[2][G];
    float2 PO[2][2];

    auto load_stage = [&](int s, int g) {
        const int tg = t0 + g * G;
#pragma unroll
        for (int q = 0; q < G; ++q) PI[s][q] = inp[(size_t)(tg + q) * IST];
#pragma unroll
        for (int u = 0; u < 2; ++u) PO[s][u] = outp[(size_t)(tg + 2 * q2 + u) * OST];
    };

    auto body = [&](int s, int g) {
        // consume stage s: trace recurrence (exact fp32), packed bf16 cvt
        float a0[G], a1[G];
#pragma unroll
        for (int q = 0; q < G; ++q) {
            tr0 = 0.5f * tr0 + PI[s][q].x;
            tr1 = 0.5f * tr1 + PI[s][q].y;
            a0[q] = tr0; a1[q] = tr1;
        }
        const unsigned w00 = pack_bf16(a0[0], a0[1]);   // row i0  , k=btr*4+{0,1}
        const unsigned w01 = pack_bf16(a0[2], a0[3]);   // row i0  , k=btr*4+{2,3}
        const unsigned w10 = pack_bf16(a1[0], a1[1]);   // row i0+1
        const unsigned w11 = pack_bf16(a1[2], a1[3]);
        const unsigned wo0 = pack_bf16(PO[s][0].x, PO[s][1].x); // row o0  , k=bo*4+2q2+{0,1}
        const unsigned wo1 = pack_bf16(PO[s][0].y, PO[s][1].y); // row o0+1

        // stage s registers are free: issue loads for group g+2 (2-deep pipeline)
        if (g + 2 < NG) load_stage(s, g + 2);

        unsigned* trl = (unsigned*)&tr_lds[s][0];
        unsigned* otl = (unsigned*)&ot_lds[s][0];
        // trace rows: adjacent swizzled dwords -> single b64 write per row
        *(uint2*)&trl[trw0]        = make_uint2(w00, w01);
        *(uint2*)&trl[trw0 + ROWD] = make_uint2(w10, w11);
        otl[otw0]        = wo0;
        otl[otw0 + ROWD] = wo1;

        block_sync_lds_only();   // LDS-only barrier: prefetch stays in flight

        const bf16x8 a = *(const bf16x8*)&ot_lds[s][ard];
#pragma unroll
        for (int j = 0; j < 4; ++j) {
            const int bn = ntb + j;
            const bf16x8 b = *(const bf16x8*)
                &tr_lds[s][bn * (32 * ROWU) + brd0 + ((khalf ^ (bn & 1)) << 3)];
            acc[j] = __builtin_amdgcn_mfma_f32_32x32x16_bf16(a, b, acc[j], 0, 0, 0);
        }
    };

    load_stage(0, 0);
    load_stage(1, 1);
    for (int gg = 0; gg < NG; gg += 2) {
        body(0, gg);
        body(1, gg + 1);
    }

    // ---- epilogue: D[row, col] -> dw[o = mt*32+row, i = (ntb+j)*32+col] ----
    float* base = dst + (size_t)(use_atomic ? (blockIdx.x % nslots) : blockIdx.x) * OUT_ELEMS;
#pragma unroll
    for (int j = 0; j < 4; ++j) {
        const int icol = (ntb + j) * 32 + l31;
#pragma unroll
        for (int r = 0; r < 16; ++r) {
            const int row = (r & 3) + 8 * (r >> 2) + 4 * khalf;
            const int o   = mt * 32 + row;
            const float v = acc[j][r];
            if (use_atomic) atomicAdd(&base[o * NIN + icol], v);
            else            base[o * NIN + icol] = v;
        }
    }
}

__global__ void zero_kernel(float* p, int n) {
    int i = blockIdx.x * blockDim.x + threadIdx.x;
    if (i < n) p[i] = 0.f;
}

__global__ __launch_bounds__(256)
void reduce_kernel(const float* __restrict__ ws, float* __restrict__ outp, int nslots) {
    const int idx = blockIdx.x * 256 + threadIdx.x;
    float s = 0.f;
    int k = 0;
    for (; k + 16 <= nslots; k += 16) {
        float v[16];
#pragma unroll
        for (int u = 0; u < 16; ++u) v[u] = ws[(size_t)(k + u) * OUT_ELEMS + idx];
#pragma unroll
        for (int u = 0; u < 16; ++u) s += v[u];
    }
    for (; k < nslots; ++k) s += ws[(size_t)k * OUT_ELEMS + idx];
    outp[idx] = s;
}

extern "C" void kernel_launch(void* const* d_in, const int* in_sizes, int n_in,
                              void* d_out, int out_size, void* d_ws, size_t ws_size,
                              hipStream_t stream) {
    const float* in   = (const float*)d_in[0];
    const float* outs = (const float*)d_in[1];
    float* out = (float*)d_out;
    float* ws  = (float*)d_ws;

    const size_t slot_bytes = (size_t)OUT_ELEMS * sizeof(float);

    if (ws_size >= (size_t)NBLOCKS * slot_bytes) {
        // plain per-block partials + reduce (preferred)
        stdp_main<<<NBLOCKS, 512, 0, stream>>>(in, outs, ws, NBLOCKS, 0);
        reduce_kernel<<<OUT_ELEMS / 256, 256, 0, stream>>>(ws, out, NBLOCKS);
    } else if (ws_size >= 16 * slot_bytes) {
        // 16 shared slots, atomic accumulation
        zero_kernel<<<(16 * OUT_ELEMS + 255) / 256, 256, 0, stream>>>(ws, 16 * OUT_ELEMS);
        stdp_main<<<NBLOCKS, 512, 0, stream>>>(in, outs, ws, 16, 1);
        reduce_kernel<<<OUT_ELEMS / 256, 256, 0, stream>>>(ws, out, 16);
    } else {
        // last resort: atomics straight into d_out
        zero_kernel<<<(OUT_ELEMS + 255) / 256, 256, 0, stream>>>(out, OUT_ELEMS);
        stdp_main<<<NBLOCKS, 512, 0, stream>>>(in, outs, out, 1, 1);
    }
}

// Round 3
// 453.807 us; speedup vs baseline: 1.0534x; 1.0491x over previous
//
#include <hip/hip_runtime.h>
#include <hip/hip_bf16.h>

// Problem constants (fixed by reference setup_inputs).
#define T_TOTAL 2048
#define BATCH   128
#define NIN     256
#define NOUT    128

// Reverse-scan formulation:
//   rtrace[t] = out[t] + 0.5*rtrace[t+1]   (reverse scan over out-spikes)
//   dw[o,i]  = sum_{t,b} rtrace[t,b,o] * in[t,b,i]
// The recurrence lives on the NOUT side; `in` feeds MFMA raw (binary -> bf16
// conversion is exact). For mfma_f32_32x32x16_bf16, lane (l31, kh) of a wave
// needs A[k]=rtrace only for b in {2kh, 2kh+1} -> each lane scans its own two
// (o,b) traces IN REGISTERS. Zero cross-lane traffic => NO LDS, NO BARRIERS.
// 8 fully independent waves per block (block = 1 CU) keep the memory queue
// continuously fed (no lockstep convoy).
#define TC      256                 // timesteps per block
#define BC      4                   // batches per block
#define WARM    32                  // reverse warm-up steps (0.5^32 ~ 2e-10)
#define G       4                   // timesteps per MFMA K-group (K = G*BC = 16)
#define NTC     (T_TOTAL / TC)      // 8
#define NBC     (BATCH / BC)        // 32
#define NBLOCKS (NTC * NBC)         // 256  (1 block/CU)
#define NG      (TC / G)            // 64 K-groups per block

#define OUT_ELEMS (NOUT * NIN)      // 32768

static_assert(NG % 2 == 0, "2-stage pipeline needs even group count");

typedef __attribute__((ext_vector_type(8)))  __bf16 bf16x8;
typedef __attribute__((ext_vector_type(2)))  __bf16 bf16x2;
typedef __attribute__((ext_vector_type(16))) float  f32x16;

// packed f32x2 -> bf16x2 (v_cvt_pk_bf16_f32 on gfx950, RTNE; exact for {0,1})
static __device__ __forceinline__ unsigned pack_bf16(float a, float b) {
    bf16x2 v = { (__bf16)a, (__bf16)b };
    union { bf16x2 v; unsigned u; } c; c.v = v; return c.u;
}

static __device__ __forceinline__ bf16x8 frag_from4(unsigned d0, unsigned d1,
                                                    unsigned d2, unsigned d3) {
    union { unsigned u[4]; bf16x8 v; } c;
    c.u[0] = d0; c.u[1] = d1; c.u[2] = d2; c.u[3] = d3; return c.v;
}

// Wave w = (mt = w&3, nh = w>>2): output tile o in [mt*32, mt*32+32),
// i in [nh*128, nh*128+128). Lane (l31 = lane&31, kh = lane>>5):
//   A-frag element j (k = kh*8+j): b_local = 2kh + (j>=4), q = j&3
//     -> lane scans rtrace for (o = mt*32+l31, b = b0+2kh) and (o, b0+2kh+1).
//   B-frag element j for tile tn:  in[t0+4g+(j&3), b0+2kh+(j>=4), (nh*4+tn)*32+l31]
//     -> direct global loads, 128B-coalesced across l31.
// 2-deep register prefetch per wave; no __syncthreads anywhere.
__global__ __launch_bounds__(512, 2)
void stdp_main(const float* __restrict__ in, const float* __restrict__ outs,
               float* __restrict__ dst, int nslots, int use_atomic)
{
    const int tid = threadIdx.x;
    const int bc  = blockIdx.x % NBC;
    const int tc  = blockIdx.x / NBC;
    const int b0  = bc * BC;
    const int t0  = tc * TC;

    const int lane = tid & 63;
    const int wv   = tid >> 6;           // 8 waves, fully independent
    const int mt   = wv & 3;             // o-tile (rows mt*32..+31)
    const int nh   = wv >> 2;            // i-half (cols nh*128..+127)
    const int l31  = lane & 31;
    const int kh   = lane >> 5;          // selects b-pair {2kh, 2kh+1}

    const size_t IST = (size_t)BATCH * NIN;    // floats per timestep in `in`
    const size_t OST = (size_t)BATCH * NOUT;

    const float* __restrict__ inW  = in   + (size_t)(b0 + 2 * kh) * NIN  + nh * 128 + l31;
    const float* __restrict__ outW = outs + (size_t)(b0 + 2 * kh) * NOUT + mt * 32  + l31;

    float rtrA = 0.f, rtrB = 0.f;        // reverse traces for b0+2kh, b0+2kh+1

    // ---- reverse warm-up over the WARM timesteps after this chunk ----
    if (tc < NTC - 1) {
        for (int tb = t0 + TC + WARM; tb > t0 + TC; tb -= 8) {
            float vA[8], vB[8];
#pragma unroll
            for (int u = 0; u < 8; ++u) {
                vA[u] = outW[(size_t)(tb - 1 - u) * OST];
                vB[u] = outW[(size_t)(tb - 1 - u) * OST + NOUT];
            }
#pragma unroll
            for (int u = 0; u < 8; ++u) {
                rtrA = vA[u] + 0.5f * rtrA;
                rtrB = vB[u] + 0.5f * rtrB;
            }
        }
    }

    f32x16 acc[4];
#pragma unroll
    for (int j = 0; j < 4; ++j) acc[j] = (f32x16)(0.f);

    // 2-stage register prefetch: A-side (out) 8 floats, B-side (in) 32 floats.
    float AO[2][8];
    float BI[2][32];

    auto load_stage = [&](int s, int g) {
        const int tg = t0 + g * G;
        // A first: feeds the serial scan at the top of body().
#pragma unroll
        for (int q = 0; q < G; ++q) {
            AO[s][q]     = outW[(size_t)(tg + q) * OST];
            AO[s][4 + q] = outW[(size_t)(tg + q) * OST + NOUT];
        }
#pragma unroll
        for (int tn = 0; tn < 4; ++tn)
#pragma unroll
            for (int be = 0; be < 2; ++be)
#pragma unroll
                for (int q = 0; q < G; ++q)
                    BI[s][tn * 8 + be * 4 + q] =
                        inW[(size_t)(tg + q) * IST + be * NIN + tn * 32];
    };

    auto body = [&](int s, int g) {
        // reverse scan over this group's 4 timesteps (descending t)
        float aA[4], aB[4];
#pragma unroll
        for (int q = 3; q >= 0; --q) {
            rtrA = AO[s][q]     + 0.5f * rtrA; aA[q] = rtrA;
            rtrB = AO[s][4 + q] + 0.5f * rtrB; aB[q] = rtrB;
        }
        const bf16x8 a = frag_from4(pack_bf16(aA[0], aA[1]), pack_bf16(aA[2], aA[3]),
                                    pack_bf16(aB[0], aB[1]), pack_bf16(aB[2], aB[3]));
        bf16x8 bfr[4];
#pragma unroll
        for (int tn = 0; tn < 4; ++tn) {
            const float* p = &BI[s][tn * 8];
            bfr[tn] = frag_from4(pack_bf16(p[0], p[1]), pack_bf16(p[2], p[3]),
                                 pack_bf16(p[4], p[5]), pack_bf16(p[6], p[7]));
        }
        // stage s registers free: issue loads for group g-2 (reverse order)
        if (g >= 2) load_stage(s, g - 2);
#pragma unroll
        for (int tn = 0; tn < 4; ++tn)
            acc[tn] = __builtin_amdgcn_mfma_f32_32x32x16_bf16(a, bfr[tn], acc[tn], 0, 0, 0);
    };

    load_stage(1, NG - 1);
    load_stage(0, NG - 2);
    for (int gg = NG - 1; gg >= 1; gg -= 2) {
        body(1, gg);
        body(0, gg - 1);
    }

    // ---- epilogue: D[row, col] -> dw[o = mt*32+row, i = (nh*4+j)*32+col] ----
    float* base = dst + (size_t)(use_atomic ? (blockIdx.x % nslots) : blockIdx.x) * OUT_ELEMS;
#pragma unroll
    for (int j = 0; j < 4; ++j) {
        const int icol = (nh * 4 + j) * 32 + l31;
#pragma unroll
        for (int r = 0; r < 16; ++r) {
            const int row = (r & 3) + 8 * (r >> 2) + 4 * kh;
            const int o   = mt * 32 + row;
            const float v = acc[j][r];
            if (use_atomic) atomicAdd(&base[o * NIN + icol], v);
            else            base[o * NIN + icol] = v;
        }
    }
}

__global__ void zero_kernel(float* p, int n) {
    int i = blockIdx.x * blockDim.x + threadIdx.x;
    if (i < n) p[i] = 0.f;
}

__global__ __launch_bounds__(256)
void reduce_kernel(const float* __restrict__ ws, float* __restrict__ outp, int nslots) {
    const int idx = blockIdx.x * 256 + threadIdx.x;
    float s = 0.f;
    int k = 0;
    for (; k + 16 <= nslots; k += 16) {
        float v[16];
#pragma unroll
        for (int u = 0; u < 16; ++u) v[u] = ws[(size_t)(k + u) * OUT_ELEMS + idx];
#pragma unroll
        for (int u = 0; u < 16; ++u) s += v[u];
    }
    for (; k < nslots; ++k) s += ws[(size_t)k * OUT_ELEMS + idx];
    outp[idx] = s;
}

extern "C" void kernel_launch(void* const* d_in, const int* in_sizes, int n_in,
                              void* d_out, int out_size, void* d_ws, size_t ws_size,
                              hipStream_t stream) {
    const float* in   = (const float*)d_in[0];
    const float* outs = (const float*)d_in[1];
    float* out = (float*)d_out;
    float* ws  = (float*)d_ws;

    const size_t slot_bytes = (size_t)OUT_ELEMS * sizeof(float);

    if (ws_size >= (size_t)NBLOCKS * slot_bytes) {
        // plain per-block partials + reduce (preferred)
        stdp_main<<<NBLOCKS, 512, 0, stream>>>(in, outs, ws, NBLOCKS, 0);
        reduce_kernel<<<OUT_ELEMS / 256, 256, 0, stream>>>(ws, out, NBLOCKS);
    } else if (ws_size >= 16 * slot_bytes) {
        // 16 shared slots, atomic accumulation
        zero_kernel<<<(16 * OUT_ELEMS + 255) / 256, 256, 0, stream>>>(ws, 16 * OUT_ELEMS);
        stdp_main<<<NBLOCKS, 512, 0, stream>>>(in, outs, ws, 16, 1);
        reduce_kernel<<<OUT_ELEMS / 256, 256, 0, stream>>>(ws, out, 16);
    } else {
        // last resort: atomics straight into d_out
        zero_kernel<<<(OUT_ELEMS + 255) / 256, 256, 0, stream>>>(out, OUT_ELEMS);
        stdp_main<<<NBLOCKS, 512, 0, stream>>>(in, outs, out, 1, 1);
    }
}